// Round 1
// baseline (278.796 us; speedup 1.0000x reference)
//
#include <hip/hip_runtime.h>

// Quanv: 3x3 VALID conv, x:(32,64,64,64) f32, w:(128,64,9) f32.
// Output layout replicates reference bug: out[((oc*B + b)*Ho + ho)*Wo + wo].
//
// R1 strategy: fp32 register-tiled direct conv (VALU-bound baseline ~123us model).
// Block 256 = 16 ho rows x 16 wo-groups; thread: 8 oc x 4 wo accumulators.
// x staged in LDS in 8-channel chunks; weights via block-uniform (scalar) loads.

#define B_   32
#define C_   64
#define H_   64
#define W_   64
#define OC_  128
#define HO_  62
#define WO_  62

#define CCH   8    // channels per LDS chunk
#define OC_PT 8    // oc per thread (== per block)
#define TY    16   // ho rows per block
#define ROWS  18   // TY + 2 halo

__global__ __launch_bounds__(256, 4)
void quanv_f32(const float* __restrict__ x, const float* __restrict__ w,
               float* __restrict__ out) {
    // +4 pad floats: tx=15 reads cols up to wo0+5=65 (values only feed masked
    // outputs, but keep the read in-bounds and deterministic).
    __shared__ float sx_raw[CCH * ROWS * W_ + 4];
    #define SX(cl, row, col) sx_raw[((cl) * ROWS + (row)) * W_ + (col)]

    const int tid = threadIdx.x;
    const int tx  = tid & 15;   // wo group
    const int ty  = tid >> 4;   // ho row within tile
    const int hot = blockIdx.x; // 0..3
    const int ocg = blockIdx.y; // 0..15
    const int b   = blockIdx.z; // 0..31

    const int row0 = hot * TY;
    const int ho   = row0 + ty;
    const int wo0  = tx * 4;

    const float* xb = x + (size_t)b * (C_ * H_ * W_);
    const float* wb = w + (size_t)(ocg * OC_PT) * (C_ * 9);

    float acc[OC_PT][4];
    #pragma unroll
    for (int o = 0; o < OC_PT; ++o)
        #pragma unroll
        for (int q = 0; q < 4; ++q) acc[o][q] = 0.f;

    for (int cc = 0; cc < C_; cc += CCH) {
        __syncthreads();
        // Stage CCH x ROWS x 64 floats = 2304 float4, 9 per thread, coalesced.
        #pragma unroll
        for (int j = 0; j < 9; ++j) {
            const int idx  = j * 256 + tid;   // 0..2303, linear over slab/4
            const int col4 = idx & 15;
            const int rowc = idx >> 4;        // 0..143
            const int row  = rowc % ROWS;
            const int cl   = rowc / ROWS;
            int gr = row0 + row;              // clamp halo rows past H (tile 3)
            if (gr > H_ - 1) gr = H_ - 1;
            const float4 v =
                *(const float4*)(xb + ((size_t)(cc + cl) * H_ + gr) * W_ + col4 * 4);
            *(float4*)(&sx_raw[idx * 4]) = v;
        }
        __syncthreads();

        for (int cl = 0; cl < CCH; ++cl) {
            // 3x6 x-window for 4 contiguous wo (ds_read_b128 + b64 per row).
            float xv[3][6];
            #pragma unroll
            for (int kh = 0; kh < 3; ++kh)
                #pragma unroll
                for (int j = 0; j < 6; ++j)
                    xv[kh][j] = SX(cl, ty + kh, wo0 + j);

            const float* wc = wb + (size_t)(cc + cl) * 9;  // block-uniform addr
            #pragma unroll
            for (int o = 0; o < OC_PT; ++o) {
                float wv[9];
                #pragma unroll
                for (int t = 0; t < 9; ++t) wv[t] = wc[(size_t)o * (C_ * 9) + t];
                #pragma unroll
                for (int kh = 0; kh < 3; ++kh)
                    #pragma unroll
                    for (int kw = 0; kw < 3; ++kw) {
                        const float wvv = wv[kh * 3 + kw];
                        #pragma unroll
                        for (int q = 0; q < 4; ++q)
                            acc[o][q] = fmaf(xv[kh][kw + q], wvv, acc[o][q]);
                    }
            }
        }
    }

    // Epilogue: out[((oc*B + b)*HO + ho)*WO + wo], masked for ho/wo >= 62.
    if (ho < HO_) {
        #pragma unroll
        for (int o = 0; o < OC_PT; ++o) {
            const int oc = ocg * OC_PT + o;
            float* op = out + ((size_t)(oc * B_ + b) * HO_ + ho) * WO_ + wo0;
            #pragma unroll
            for (int q = 0; q < 4; ++q)
                if (wo0 + q < WO_) op[q] = acc[o][q];
        }
    }
    #undef SX
}

extern "C" void kernel_launch(void* const* d_in, const int* in_sizes, int n_in,
                              void* d_out, int out_size, void* d_ws, size_t ws_size,
                              hipStream_t stream) {
    const float* x = (const float*)d_in[0];   // 32*64*64*64
    const float* w = (const float*)d_in[1];   // 128*64*9
    float* out = (float*)d_out;               // 128*32*62*62 (oc-major layout)

    dim3 grid(4, 16, 32);   // ho tiles, oc groups, batch
    dim3 block(256);
    quanv_f32<<<grid, block, 0, stream>>>(x, w, out);
}

// Round 2
// 115.086 us; speedup vs baseline: 2.4225x; 2.4225x over previous
//
#include <hip/hip_runtime.h>

// Quanv: 3x3 VALID conv, x:(32,64,64,64) f32, w:(128,64,9) f32.
// Output layout replicates reference bug: out[((oc*B + b)*Ho + ho)*Wo + wo].
//
// R2: bf16 MFMA implicit GEMM, tap-decomposed (9 shifted GEMMs with K=C=64).
//  - prep1: x -> xT[b][h][col][c] bf16, c stored as 8 chunks of 8, chunk q at
//           position q ^ (col&7)  (XOR swizzle => ds_read_b128 2-way max AND
//           verbatim global_load_lds staging).
//  - prep2: w -> wT[tap][oc][c] bf16, chunk q at q ^ (oc&7).
//  - main: 512 blocks (16 ho-tiles x 32 b); block = 4 output rows x 128 oc x
//          64 wo. Wave = 1 row; 8x4 tiles of mfma_f32_16x16x32_bf16;
//          acc 128 VGPR. Weights for tap+1 prefetched into registers during
//          compute; LDS = 48 KB x-tile + 16 KB w-tap = 64 KB exactly.
// Fallback to fp32 direct conv if ws_size too small.

typedef __attribute__((ext_vector_type(8))) short short8;
typedef __attribute__((ext_vector_type(4))) float f32x4;
typedef __attribute__((ext_vector_type(4))) unsigned int uint4v;

__device__ __forceinline__ unsigned short f2bf(float f) {
    unsigned u = __builtin_bit_cast(unsigned, f);
    u = (u + 0x7FFFu + ((u >> 16) & 1u)) >> 16;   // RNE
    return (unsigned short)u;
}

__device__ __forceinline__ void glds16(const void* g, void* s) {
    __builtin_amdgcn_global_load_lds(
        (const __attribute__((address_space(1))) unsigned int*)g,
        (__attribute__((address_space(3))) unsigned int*)s, 16, 0, 0);
}

// ---------- prep 1: x (b,c,h,w) f32 -> xT[b][h][col][c-swizzled] bf16 ----------
__global__ __launch_bounds__(256)
void transpose_x(const float* __restrict__ x, char* __restrict__ xT) {
    __shared__ float tile[64][65];          // [c][col], +1 pad
    const int tid = threadIdx.x;
    const int h = blockIdx.x, b = blockIdx.y;

    #pragma unroll
    for (int i = 0; i < 4; ++i) {
        const int idx = i * 256 + tid;
        const int c = idx >> 4, j = idx & 15;
        const float4 v = *(const float4*)(x + (size_t)(((b * 64 + c) * 64 + h) * 64 + j * 4));
        tile[c][j * 4 + 0] = v.x; tile[c][j * 4 + 1] = v.y;
        tile[c][j * 4 + 2] = v.z; tile[c][j * 4 + 3] = v.w;
    }
    __syncthreads();

    #pragma unroll
    for (int i = 0; i < 2; ++i) {
        const int idx = i * 256 + tid;
        const int col = idx >> 3, q = idx & 7;
        unsigned int wds[4];
        #pragma unroll
        for (int jj = 0; jj < 4; ++jj) {
            const unsigned short lo = f2bf(tile[q * 8 + 2 * jj + 0][col]);
            const unsigned short hi = f2bf(tile[q * 8 + 2 * jj + 1][col]);
            wds[jj] = (unsigned)lo | ((unsigned)hi << 16);
        }
        uint4v v; v[0] = wds[0]; v[1] = wds[1]; v[2] = wds[2]; v[3] = wds[3];
        *(uint4v*)(xT + (size_t)(((b * 64 + h) * 64 + col) * 128) + ((q ^ (col & 7)) * 16)) = v;
    }
}

// ---------- prep 2: w (oc, c, 9) f32 -> wT[tap][oc][c-swizzled] bf16 ----------
__global__ __launch_bounds__(256)
void pack_w(const float* __restrict__ w, char* __restrict__ wT) {
    const int id = blockIdx.x * 256 + threadIdx.x;   // 0..9215
    const int t = id >> 10;
    const int rem = id & 1023;
    const int oc = rem >> 3, q = rem & 7;
    unsigned int wds[4];
    #pragma unroll
    for (int jj = 0; jj < 4; ++jj) {
        const unsigned short lo = f2bf(w[(size_t)oc * 576 + (q * 8 + 2 * jj + 0) * 9 + t]);
        const unsigned short hi = f2bf(w[(size_t)oc * 576 + (q * 8 + 2 * jj + 1) * 9 + t]);
        wds[jj] = (unsigned)lo | ((unsigned)hi << 16);
    }
    uint4v v; v[0] = wds[0]; v[1] = wds[1]; v[2] = wds[2]; v[3] = wds[3];
    *(uint4v*)(wT + (size_t)(t * 16384 + oc * 128) + ((q ^ (oc & 7)) * 16)) = v;
}

// ---------- main MFMA kernel ----------
__global__ __launch_bounds__(256, 2)
void quanv_mfma(const char* __restrict__ xT, const char* __restrict__ wT,
                float* __restrict__ out) {
    __shared__ __align__(16) char lds[65536];
    char* sx = lds;            // 48 KB: [6 rows][64 col][128B c-block swizzled]
    char* sw = lds + 49152;    // 16 KB: [128 oc][128B c-block swizzled]

    const int tid = threadIdx.x;
    const int lane = tid & 63;
    const int wid = tid >> 6;
    const int hot = blockIdx.x;   // 0..15
    const int b   = blockIdx.y;   // 0..31
    const int ho0 = hot * 4;

    // stage x: 6 rows x 8 KB = 48 chunks of 1 KB (async, direct to LDS)
    for (int k = wid; k < 48; k += 4) {
        const int r = k >> 3, sub = k & 7;
        int gr = ho0 + r; if (gr > 63) gr = 63;
        glds16(xT + (size_t)((b * 64 + gr) * 8192 + sub * 1024 + lane * 16),
               sx + k * 1024);
    }
    // stage weights for tap 0: 16 chunks of 1 KB
    for (int k = wid; k < 16; k += 4)
        glds16(wT + (size_t)(k * 1024 + lane * 16), sw + k * 1024);
    __syncthreads();   // drains vmcnt then barrier

    const int l15 = lane & 15;
    const int quad = lane >> 4;
    const int r = wid;            // output row within tile
    const int ho = ho0 + r;

    f32x4 acc[8][4];
    #pragma unroll
    for (int mt = 0; mt < 8; ++mt)
        #pragma unroll
        for (int nt = 0; nt < 4; ++nt)
            acc[mt][nt] = (f32x4){0.f, 0.f, 0.f, 0.f};

    #pragma unroll
    for (int tap = 0; tap < 9; ++tap) {
        const int kh = tap / 3, kw = tap % 3;

        // register prefetch of next tap's weights (latency hidden by MFMA)
        uint4v pf[4];
        if (tap < 8) {
            #pragma unroll
            for (int i = 0; i < 4; ++i)
                pf[i] = *(const uint4v*)(wT + (size_t)((tap + 1) * 16384 +
                                                      (wid * 4 + i) * 1024 + lane * 16));
        }

        #pragma unroll
        for (int s = 0; s < 2; ++s) {           // K halves (c 0..31, 32..63)
            const int q = s * 4 + quad;         // c-chunk index 0..7
            short8 a[8], bf[4];
            const int abase = l15 * 128 + ((q ^ (l15 & 7)) * 16);
            #pragma unroll
            for (int mt = 0; mt < 8; ++mt)
                a[mt] = *(const short8*)(sw + abase + mt * 2048);
            const int cb = kw + l15;            // lane's column (before n-tile)
            const int bbase = (r + kh) * 8192 + cb * 128 + ((q ^ (cb & 7)) * 16);
            #pragma unroll
            for (int nt = 0; nt < 4; ++nt)
                bf[nt] = *(const short8*)(sx + bbase + nt * 2048);
            #pragma unroll
            for (int mt = 0; mt < 8; ++mt)
                #pragma unroll
                for (int nt = 0; nt < 4; ++nt)
                    acc[mt][nt] = __builtin_amdgcn_mfma_f32_16x16x32_bf16(
                        a[mt], bf[nt], acc[mt][nt], 0, 0, 0);
        }

        if (tap < 8) {
            __syncthreads();                    // all waves done reading sw
            #pragma unroll
            for (int i = 0; i < 4; ++i)
                *(uint4v*)(sw + (wid * 4 + i) * 1024 + lane * 16) = pf[i];
            __syncthreads();                    // new tap weights visible
        }
    }

    // epilogue: C/D layout col=lane&15 (wo), row=quad*4+reg (oc within tile)
    if (ho < 62) {
        #pragma unroll
        for (int mt = 0; mt < 8; ++mt) {
            #pragma unroll
            for (int i = 0; i < 4; ++i) {
                const int oc = mt * 16 + quad * 4 + i;
                float* op = out + ((size_t)(oc * 32 + b) * 62 + ho) * 62;
                #pragma unroll
                for (int nt = 0; nt < 4; ++nt) {
                    const int wo = nt * 16 + l15;
                    if (wo < 62) op[wo] = acc[mt][nt][i];
                }
            }
        }
    }
}

// ---------- fallback: R1 fp32 direct conv (used only if ws too small) ----------
#define CCH   8
#define OC_PT 8
#define ROWS  18
__global__ __launch_bounds__(256, 4)
void quanv_f32(const float* __restrict__ x, const float* __restrict__ w,
               float* __restrict__ out) {
    __shared__ float sx_raw[CCH * ROWS * 64 + 4];
    #define SX(cl, row, col) sx_raw[((cl) * ROWS + (row)) * 64 + (col)]
    const int tid = threadIdx.x;
    const int tx = tid & 15, ty = tid >> 4;
    const int hot = blockIdx.x, ocg = blockIdx.y, b = blockIdx.z;
    const int row0 = hot * 16, ho = row0 + ty, wo0 = tx * 4;
    const float* xb = x + (size_t)b * (64 * 64 * 64);
    const float* wb = w + (size_t)(ocg * OC_PT) * 576;
    float acc[OC_PT][4];
    #pragma unroll
    for (int o = 0; o < OC_PT; ++o)
        #pragma unroll
        for (int q = 0; q < 4; ++q) acc[o][q] = 0.f;
    for (int cc = 0; cc < 64; cc += CCH) {
        __syncthreads();
        #pragma unroll
        for (int j = 0; j < 9; ++j) {
            const int idx = j * 256 + tid;
            const int col4 = idx & 15, rowc = idx >> 4;
            const int row = rowc % ROWS, cl = rowc / ROWS;
            int gr = row0 + row; if (gr > 63) gr = 63;
            *(float4*)(&sx_raw[idx * 4]) =
                *(const float4*)(xb + ((size_t)(cc + cl) * 64 + gr) * 64 + col4 * 4);
        }
        __syncthreads();
        for (int cl = 0; cl < CCH; ++cl) {
            float xv[3][6];
            #pragma unroll
            for (int kh = 0; kh < 3; ++kh)
                #pragma unroll
                for (int j = 0; j < 6; ++j) xv[kh][j] = SX(cl, ty + kh, wo0 + j);
            const float* wc = wb + (size_t)(cc + cl) * 9;
            #pragma unroll
            for (int o = 0; o < OC_PT; ++o) {
                float wv[9];
                #pragma unroll
                for (int t = 0; t < 9; ++t) wv[t] = wc[(size_t)o * 576 + t];
                #pragma unroll
                for (int kh = 0; kh < 3; ++kh)
                    #pragma unroll
                    for (int kw = 0; kw < 3; ++kw) {
                        const float wvv = wv[kh * 3 + kw];
                        #pragma unroll
                        for (int q = 0; q < 4; ++q)
                            acc[o][q] = fmaf(xv[kh][kw + q], wvv, acc[o][q]);
                    }
            }
        }
    }
    if (ho < 62) {
        #pragma unroll
        for (int o = 0; o < OC_PT; ++o) {
            const int oc = ocg * OC_PT + o;
            float* op = out + ((size_t)(oc * 32 + b) * 62 + ho) * 62 + wo0;
            #pragma unroll
            for (int q = 0; q < 4; ++q)
                if (wo0 + q < 62) op[q] = acc[o][q];
        }
    }
    #undef SX
}

extern "C" void kernel_launch(void* const* d_in, const int* in_sizes, int n_in,
                              void* d_out, int out_size, void* d_ws, size_t ws_size,
                              hipStream_t stream) {
    const float* x = (const float*)d_in[0];
    const float* w = (const float*)d_in[1];
    float* out = (float*)d_out;

    const size_t XT_BYTES = 16777216;   // 32*64*64*64 bf16
    const size_t WT_BYTES = 147456;     // 9*128*64 bf16

    if (ws_size >= XT_BYTES + WT_BYTES) {
        char* xT = (char*)d_ws;
        char* wT = (char*)d_ws + XT_BYTES;
        transpose_x<<<dim3(64, 32), 256, 0, stream>>>(x, xT);
        pack_w<<<36, 256, 0, stream>>>(w, wT);
        quanv_mfma<<<dim3(16, 32), 256, 0, stream>>>(xT, wT, out);
    } else {
        quanv_f32<<<dim3(4, 16, 32), 256, 0, stream>>>(x, w, out);
    }
}